// Round 7
// baseline (60.469 us; speedup 1.0000x reference)
//
#include <hip/hip_runtime.h>
#include <hip/hip_bf16.h>
#include <math.h>

typedef __attribute__((ext_vector_type(8))) short short8;
typedef __attribute__((ext_vector_type(4))) float f32x4;

__device__ __forceinline__ unsigned pkbf2(float lo, float hi) {
    __hip_bfloat162 h = __float22bfloat162_rn(make_float2(lo, hi));
    union { __hip_bfloat162 h; unsigned u; } c;
    c.h = h;
    return c.u;
}

// One fused kernel: 512 blocks (one per batch) x 512 threads (8 waves).
// Wave w owns output cols [w*32, w*32+32). W2 B-fragments built in-register
// straight from f32 W2 (L2-hot). Layer-1 via MFMA (K=4 padded), 4 row-slices
// of 64 through 32 KB LDS, layer-2 full-K MFMA, fused masked pool + head.
__global__ __launch_bounds__(512, 4) void actor_kernel(
    const float* __restrict__ obs,  const float* __restrict__ obst,
    const float* __restrict__ eps,  const float* __restrict__ W1,
    const float* __restrict__ b1,   const float* __restrict__ W2,
    const float* __restrict__ b2,   const float* __restrict__ muW,
    const float* __restrict__ mub,  const float* __restrict__ lsW,
    const float* __restrict__ lsb,  float* __restrict__ out)
{
    __shared__ __align__(16) short sA[4 * 64 * 64];   // 4 pages x (64 rows x 64 j), 32 KB
    __shared__ float sVeh[256];
    __shared__ float sRed[8][4];

    const int b = blockIdx.x;
    const int t = threadIdx.x;
    const int l = t & 63;
    const int w = t >> 6;          // wave: output cols [w*32, w*32+32)
    const int g = l >> 4;
    const int ln = l & 15;

    // per-batch bias vector veh@W1[:15]+b1
    if (t < 256) {
        float a = b1[t];
#pragma unroll
        for (int i = 0; i < 15; ++i) a = fmaf(obs[b * 15 + i], W1[i * 256 + t], a);
        sVeh[t] = a;
    }

    // ---- layer-2 B-fragments from W2 (f32, row-major [k][col]) ----
    // frag (kt,c): elem j = W2[kt*32 + g*8 + j][(w*2+c)*16 + ln]
    short8 bfr[8][2];
#pragma unroll
    for (int kt = 0; kt < 8; ++kt) {
#pragma unroll
        for (int c = 0; c < 2; ++c) {
            const float* p = W2 + (size_t)(kt * 32 + g * 8) * 256 + (w * 2 + c) * 16 + ln;
            float f0 = p[0 * 256], f1 = p[1 * 256], f2 = p[2 * 256], f3 = p[3 * 256];
            float f4 = p[4 * 256], f5 = p[5 * 256], f6 = p[6 * 256], f7 = p[7 * 256];
            union { short8 s; unsigned u[4]; } tv;
            tv.u[0] = pkbf2(f0, f1);
            tv.u[1] = pkbf2(f2, f3);
            tv.u[2] = pkbf2(f4, f5);
            tv.u[3] = pkbf2(f6, f7);
            bfr[kt][c] = tv.s;
        }
    }

    // ---- layer-1 A-fragments (W1obst^T, K=32 with only k<4 nonzero) ----
    short8 a1[2];
#pragma unroll
    for (int ji = 0; ji < 2; ++ji) {
        union { short8 s; unsigned u[4]; } tv;
        tv.u[0] = 0u; tv.u[1] = 0u; tv.u[2] = 0u; tv.u[3] = 0u;
        if (g == 0) {
            int j = (w * 2 + ji) * 16 + ln;
            tv.u[0] = pkbf2(W1[15 * 256 + j], W1[16 * 256 + j]);
            tv.u[1] = pkbf2(W1[17 * 256 + j], W1[18 * 256 + j]);
        }
        a1[ji] = tv.s;
    }

    // loop-invariant pooling weights for this lane's 2 cols
    float bb[2]; float2 mwv[2], lwv[2];
#pragma unroll
    for (int c = 0; c < 2; ++c) {
        int col = w * 32 + c * 16 + ln;
        bb[c] = b2[col];
        mwv[c] = *reinterpret_cast<const float2*>(muW + col * 2);
        lwv[c] = *reinterpret_cast<const float2*>(lsW + col * 2);
    }

    const float* ob = obst + b * 1280;
    const float* maskbase = ob + 1024;

    // layer-1 B-fragments (obstacle rows, K=4 in low k-slots) for one 64-row slice
    short8 bf1[4];
    auto loadB1 = [&](int q) {
#pragma unroll
        for (int nt = 0; nt < 4; ++nt) {
            union { short8 s; unsigned u[4]; } tv;
            tv.u[0] = 0u; tv.u[1] = 0u; tv.u[2] = 0u; tv.u[3] = 0u;
            if (l < 16) {
                const float* pp = ob + q * 64 + nt * 16 + l;
                tv.u[0] = pkbf2(pp[0], pp[256]);
                tv.u[1] = pkbf2(pp[512], pp[768]);
            }
            bf1[nt] = tv.s;
        }
    };
    loadB1(0);

    f32x4 acc[4][2];
#pragma unroll
    for (int m = 0; m < 4; ++m)
#pragma unroll
        for (int c = 0; c < 2; ++c) acc[m][c] = (f32x4){0.f, 0.f, 0.f, 0.f};
    float m0 = 0.f, m1 = 0.f, s0 = 0.f, s1 = 0.f;

    __syncthreads();   // sVeh ready

    for (int q = 0; q < 4; ++q) {
        // ---- layer 1: this wave's 2 j-tiles x 4 n-tiles -> LDS ----
#pragma unroll
        for (int ji = 0; ji < 2; ++ji) {
            int jt = w * 2 + ji;
            int j0 = jt * 16 + g * 4;
            f32x4 bias = *reinterpret_cast<const f32x4*>(&sVeh[j0]);
            unsigned page = (unsigned)(j0 >> 6) * 8192;
            unsigned jbyte = (unsigned)((j0 & 63) * 2);
#pragma unroll
            for (int nt = 0; nt < 4; ++nt) {
                f32x4 d = (f32x4){0.f, 0.f, 0.f, 0.f};
                d = __builtin_amdgcn_mfma_f32_16x16x32_bf16(a1[ji], bf1[nt], d, 0, 0, 0);
                int n = nt * 16 + ln;
                uint2 u;
                u.x = pkbf2(fmaxf(d[0] + bias[0], 0.f), fmaxf(d[1] + bias[1], 0.f));
                u.y = pkbf2(fmaxf(d[2] + bias[2], 0.f), fmaxf(d[3] + bias[3], 0.f));
                unsigned off = page + (unsigned)(n * 128) + (jbyte ^ ((unsigned)((n & 7) << 4)));
                *reinterpret_cast<uint2*>((char*)sA + off) = u;
            }
        }
        if (q < 3) loadB1(q + 1);   // prefetch next slice's obstacle frags
        __syncthreads();            // h1 slice ready

        // ---- layer 2: full K, B from registers, A from LDS ----
#pragma unroll
        for (int kt = 0; kt < 8; ++kt) {
            unsigned page = (unsigned)(kt >> 1) * 8192;
            unsigned kbyte = (unsigned)((kt & 1) * 64 + g * 16);
#pragma unroll
            for (int m = 0; m < 4; ++m) {
                int n = m * 16 + ln;
                unsigned off = page + (unsigned)(n * 128) + (kbyte ^ ((unsigned)((n & 7) << 4)));
                short8 afr = *reinterpret_cast<const short8*>((const char*)sA + off);
#pragma unroll
                for (int c = 0; c < 2; ++c)
                    acc[m][c] = __builtin_amdgcn_mfma_f32_16x16x32_bf16(afr, bfr[kt][c], acc[m][c], 0, 0, 0);
            }
        }

        // ---- masked pool of this slice, fused with muW/lsW dot; reset acc ----
        const float* maskp = maskbase + q * 64;
#pragma unroll
        for (int c = 0; c < 2; ++c) {
            float p = 0.f;
#pragma unroll
            for (int m = 0; m < 4; ++m) {
                float4 M = *reinterpret_cast<const float4*>(maskp + m * 16 + g * 4);
                f32x4 v = acc[m][c];
                p = fmaf(M.x, fmaxf(v[0] + bb[c], 0.f), p);
                p = fmaf(M.y, fmaxf(v[1] + bb[c], 0.f), p);
                p = fmaf(M.z, fmaxf(v[2] + bb[c], 0.f), p);
                p = fmaf(M.w, fmaxf(v[3] + bb[c], 0.f), p);
                acc[m][c] = (f32x4){0.f, 0.f, 0.f, 0.f};
            }
            p += __shfl_xor(p, 16);
            p += __shfl_xor(p, 32);          // all lanes: pooled partial for col
            m0 = fmaf(p, mwv[c].x, m0);
            m1 = fmaf(p, mwv[c].y, m1);
            s0 = fmaf(p, lwv[c].x, s0);
            s1 = fmaf(p, lwv[c].y, s1);
        }
        if (q < 3) __syncthreads();          // LDS reuse guard
    }

    // ---- block-level reduction + head ----
#pragma unroll
    for (int off = 1; off < 16; off <<= 1) {
        m0 += __shfl_xor(m0, off);
        m1 += __shfl_xor(m1, off);
        s0 += __shfl_xor(s0, off);
        s1 += __shfl_xor(s1, off);
    }
    if (l == 0) { sRed[w][0] = m0; sRed[w][1] = m1; sRed[w][2] = s0; sRed[w][3] = s1; }
    __syncthreads();
    if (t == 0) {
        float M0 = 0.f, M1 = 0.f, S0 = 0.f, S1 = 0.f;
#pragma unroll
        for (int ww = 0; ww < 8; ++ww) {
            M0 += sRed[ww][0]; M1 += sRed[ww][1];
            S0 += sRed[ww][2]; S1 += sRed[ww][3];
        }
        float mu0 = M0 + mub[0], mu1 = M1 + mub[1];
        float ls0 = fminf(fmaxf(S0 + lsb[0], -20.f), 2.f);
        float ls1 = fminf(fmaxf(S1 + lsb[1], -20.f), 2.f);
        float e0 = eps[b * 2 + 0], e1 = eps[b * 2 + 1];
        float a0 = fmaf(expf(ls0), e0, mu0);
        float a1v = fmaf(expf(ls1), e1, mu1);
        float logp = -0.5f * (e0 * e0 + e1 * e1) - (ls0 + ls1) - 1.8378770664093453f;
        float x0 = -2.f * a0, x1 = -2.f * a1v;
        float sp0 = fmaxf(x0, 0.f) + log1pf(expf(-fabsf(x0)));
        float sp1 = fmaxf(x1, 0.f) + log1pf(expf(-fabsf(x1)));
        logp -= 2.f * (0.6931471805599453f - a0 - sp0);
        logp -= 2.f * (0.6931471805599453f - a1v - sp1);
        out[b * 2 + 0] = tanhf(a0);
        out[b * 2 + 1] = tanhf(a1v);
        out[1024 + b] = logp;
    }
}

extern "C" void kernel_launch(void* const* d_in, const int* in_sizes, int n_in,
                              void* d_out, int out_size, void* d_ws, size_t ws_size,
                              hipStream_t stream) {
    const float* obs  = (const float*)d_in[0];
    const float* obst = (const float*)d_in[1];
    const float* eps  = (const float*)d_in[2];
    const float* W1   = (const float*)d_in[3];
    const float* b1   = (const float*)d_in[4];
    const float* W2   = (const float*)d_in[5];
    const float* b2   = (const float*)d_in[6];
    const float* muW  = (const float*)d_in[7];
    const float* mub  = (const float*)d_in[8];
    const float* lsW  = (const float*)d_in[9];
    const float* lsb  = (const float*)d_in[10];
    float* out = (float*)d_out;

    actor_kernel<<<512, 512, 0, stream>>>(obs, obst, eps, W1, b1, W2, b2,
                                          muW, mub, lsW, lsb, out);
}

// Round 8
// 36.190 us; speedup vs baseline: 1.6709x; 1.6709x over previous
//
#include <hip/hip_runtime.h>
#include <hip/hip_bf16.h>
#include <math.h>

typedef __attribute__((ext_vector_type(8))) short short8;
typedef __attribute__((ext_vector_type(4))) float f32x4;

__device__ __forceinline__ unsigned pkbf2(float lo, float hi) {
    __hip_bfloat162 h = __float22bfloat162_rn(make_float2(lo, hi));
    union { __hip_bfloat162 h; unsigned u; } c;
    c.h = h;
    return c.u;
}

// One fused kernel: 512 blocks (one per batch) x 512 threads (8 waves).
// Wave w owns output cols [w*32, w*32+32). W2 B-fragments built in-register
// straight from f32 W2 (L2-hot). Layer-1 via MFMA (K=4 padded), 4 row-slices
// of 64 through 32 KB LDS, layer-2 full-K MFMA, fused masked pool + head.
// NOTE: __launch_bounds__(512,2) — the 256-reg budget is REQUIRED for the
// 64-VGPR bfr cache; (512,4) spills it to scratch (R7: 54 MB FETCH, +23 µs).
__global__ __launch_bounds__(512, 2) void actor_kernel(
    const float* __restrict__ obs,  const float* __restrict__ obst,
    const float* __restrict__ eps,  const float* __restrict__ W1,
    const float* __restrict__ b1,   const float* __restrict__ W2,
    const float* __restrict__ b2,   const float* __restrict__ muW,
    const float* __restrict__ mub,  const float* __restrict__ lsW,
    const float* __restrict__ lsb,  float* __restrict__ out)
{
    __shared__ __align__(16) short sA[4 * 64 * 64];   // 4 pages x (64 rows x 64 j), 32 KB
    __shared__ float sVeh[256];
    __shared__ float sRed[8][4];

    const int b = blockIdx.x;
    const int t = threadIdx.x;
    const int l = t & 63;
    const int w = t >> 6;          // wave: output cols [w*32, w*32+32)
    const int g = l >> 4;
    const int ln = l & 15;

    // per-batch bias vector veh@W1[:15]+b1
    if (t < 256) {
        float a = b1[t];
#pragma unroll
        for (int i = 0; i < 15; ++i) a = fmaf(obs[b * 15 + i], W1[i * 256 + t], a);
        sVeh[t] = a;
    }

    // ---- layer-2 B-fragments from W2 (f32, row-major [k][col]) ----
    // frag (kt,c): elem j = W2[kt*32 + g*8 + j][(w*2+c)*16 + ln]
    short8 bfr[8][2];
#pragma unroll
    for (int kt = 0; kt < 8; ++kt) {
#pragma unroll
        for (int c = 0; c < 2; ++c) {
            const float* p = W2 + (size_t)(kt * 32 + g * 8) * 256 + (w * 2 + c) * 16 + ln;
            float f0 = p[0 * 256], f1 = p[1 * 256], f2 = p[2 * 256], f3 = p[3 * 256];
            float f4 = p[4 * 256], f5 = p[5 * 256], f6 = p[6 * 256], f7 = p[7 * 256];
            union { short8 s; unsigned u[4]; } tv;
            tv.u[0] = pkbf2(f0, f1);
            tv.u[1] = pkbf2(f2, f3);
            tv.u[2] = pkbf2(f4, f5);
            tv.u[3] = pkbf2(f6, f7);
            bfr[kt][c] = tv.s;
        }
    }

    // ---- layer-1 A-fragments (W1obst^T, K=32 with only k<4 nonzero) ----
    short8 a1[2];
#pragma unroll
    for (int ji = 0; ji < 2; ++ji) {
        union { short8 s; unsigned u[4]; } tv;
        tv.u[0] = 0u; tv.u[1] = 0u; tv.u[2] = 0u; tv.u[3] = 0u;
        if (g == 0) {
            int j = (w * 2 + ji) * 16 + ln;
            tv.u[0] = pkbf2(W1[15 * 256 + j], W1[16 * 256 + j]);
            tv.u[1] = pkbf2(W1[17 * 256 + j], W1[18 * 256 + j]);
        }
        a1[ji] = tv.s;
    }

    // loop-invariant pooling weights for this lane's 2 cols
    float bb[2]; float2 mwv[2], lwv[2];
#pragma unroll
    for (int c = 0; c < 2; ++c) {
        int col = w * 32 + c * 16 + ln;
        bb[c] = b2[col];
        mwv[c] = *reinterpret_cast<const float2*>(muW + col * 2);
        lwv[c] = *reinterpret_cast<const float2*>(lsW + col * 2);
    }

    const float* ob = obst + b * 1280;
    const float* maskbase = ob + 1024;

    // layer-1 B-fragments (obstacle rows, K=4 in low k-slots) for one 64-row slice
    short8 bf1[4];
    auto loadB1 = [&](int q) {
#pragma unroll
        for (int nt = 0; nt < 4; ++nt) {
            union { short8 s; unsigned u[4]; } tv;
            tv.u[0] = 0u; tv.u[1] = 0u; tv.u[2] = 0u; tv.u[3] = 0u;
            if (l < 16) {
                const float* pp = ob + q * 64 + nt * 16 + l;
                tv.u[0] = pkbf2(pp[0], pp[256]);
                tv.u[1] = pkbf2(pp[512], pp[768]);
            }
            bf1[nt] = tv.s;
        }
    };
    loadB1(0);

    f32x4 acc[4][2];
#pragma unroll
    for (int m = 0; m < 4; ++m)
#pragma unroll
        for (int c = 0; c < 2; ++c) acc[m][c] = (f32x4){0.f, 0.f, 0.f, 0.f};
    float m0 = 0.f, m1 = 0.f, s0 = 0.f, s1 = 0.f;

    __syncthreads();   // sVeh ready

    for (int q = 0; q < 4; ++q) {
        // ---- layer 1: this wave's 2 j-tiles x 4 n-tiles -> LDS ----
#pragma unroll
        for (int ji = 0; ji < 2; ++ji) {
            int jt = w * 2 + ji;
            int j0 = jt * 16 + g * 4;
            f32x4 bias = *reinterpret_cast<const f32x4*>(&sVeh[j0]);
            unsigned page = (unsigned)(j0 >> 6) * 8192;
            unsigned jbyte = (unsigned)((j0 & 63) * 2);
#pragma unroll
            for (int nt = 0; nt < 4; ++nt) {
                f32x4 d = (f32x4){0.f, 0.f, 0.f, 0.f};
                d = __builtin_amdgcn_mfma_f32_16x16x32_bf16(a1[ji], bf1[nt], d, 0, 0, 0);
                int n = nt * 16 + ln;
                uint2 u;
                u.x = pkbf2(fmaxf(d[0] + bias[0], 0.f), fmaxf(d[1] + bias[1], 0.f));
                u.y = pkbf2(fmaxf(d[2] + bias[2], 0.f), fmaxf(d[3] + bias[3], 0.f));
                unsigned off = page + (unsigned)(n * 128) + (jbyte ^ ((unsigned)((n & 7) << 4)));
                *reinterpret_cast<uint2*>((char*)sA + off) = u;
            }
        }
        if (q < 3) loadB1(q + 1);   // prefetch next slice's obstacle frags
        __syncthreads();            // h1 slice ready

        // ---- layer 2: full K, B from registers, A from LDS ----
#pragma unroll
        for (int kt = 0; kt < 8; ++kt) {
            unsigned page = (unsigned)(kt >> 1) * 8192;
            unsigned kbyte = (unsigned)((kt & 1) * 64 + g * 16);
#pragma unroll
            for (int m = 0; m < 4; ++m) {
                int n = m * 16 + ln;
                unsigned off = page + (unsigned)(n * 128) + (kbyte ^ ((unsigned)((n & 7) << 4)));
                short8 afr = *reinterpret_cast<const short8*>((const char*)sA + off);
#pragma unroll
                for (int c = 0; c < 2; ++c)
                    acc[m][c] = __builtin_amdgcn_mfma_f32_16x16x32_bf16(afr, bfr[kt][c], acc[m][c], 0, 0, 0);
            }
        }

        // ---- masked pool of this slice, fused with muW/lsW dot; reset acc ----
        const float* maskp = maskbase + q * 64;
#pragma unroll
        for (int c = 0; c < 2; ++c) {
            float p = 0.f;
#pragma unroll
            for (int m = 0; m < 4; ++m) {
                float4 M = *reinterpret_cast<const float4*>(maskp + m * 16 + g * 4);
                f32x4 v = acc[m][c];
                p = fmaf(M.x, fmaxf(v[0] + bb[c], 0.f), p);
                p = fmaf(M.y, fmaxf(v[1] + bb[c], 0.f), p);
                p = fmaf(M.z, fmaxf(v[2] + bb[c], 0.f), p);
                p = fmaf(M.w, fmaxf(v[3] + bb[c], 0.f), p);
                acc[m][c] = (f32x4){0.f, 0.f, 0.f, 0.f};
            }
            p += __shfl_xor(p, 16);
            p += __shfl_xor(p, 32);          // all lanes: pooled partial for col
            m0 = fmaf(p, mwv[c].x, m0);
            m1 = fmaf(p, mwv[c].y, m1);
            s0 = fmaf(p, lwv[c].x, s0);
            s1 = fmaf(p, lwv[c].y, s1);
        }
        if (q < 3) __syncthreads();          // LDS reuse guard
    }

    // ---- block-level reduction + head ----
#pragma unroll
    for (int off = 1; off < 16; off <<= 1) {
        m0 += __shfl_xor(m0, off);
        m1 += __shfl_xor(m1, off);
        s0 += __shfl_xor(s0, off);
        s1 += __shfl_xor(s1, off);
    }
    if (l == 0) { sRed[w][0] = m0; sRed[w][1] = m1; sRed[w][2] = s0; sRed[w][3] = s1; }
    __syncthreads();
    if (t == 0) {
        float M0 = 0.f, M1 = 0.f, S0 = 0.f, S1 = 0.f;
#pragma unroll
        for (int ww = 0; ww < 8; ++ww) {
            M0 += sRed[ww][0]; M1 += sRed[ww][1];
            S0 += sRed[ww][2]; S1 += sRed[ww][3];
        }
        float mu0 = M0 + mub[0], mu1 = M1 + mub[1];
        float ls0 = fminf(fmaxf(S0 + lsb[0], -20.f), 2.f);
        float ls1 = fminf(fmaxf(S1 + lsb[1], -20.f), 2.f);
        float e0 = eps[b * 2 + 0], e1 = eps[b * 2 + 1];
        float a0 = fmaf(expf(ls0), e0, mu0);
        float a1v = fmaf(expf(ls1), e1, mu1);
        float logp = -0.5f * (e0 * e0 + e1 * e1) - (ls0 + ls1) - 1.8378770664093453f;
        float x0 = -2.f * a0, x1 = -2.f * a1v;
        float sp0 = fmaxf(x0, 0.f) + log1pf(expf(-fabsf(x0)));
        float sp1 = fmaxf(x1, 0.f) + log1pf(expf(-fabsf(x1)));
        logp -= 2.f * (0.6931471805599453f - a0 - sp0);
        logp -= 2.f * (0.6931471805599453f - a1v - sp1);
        out[b * 2 + 0] = tanhf(a0);
        out[b * 2 + 1] = tanhf(a1v);
        out[1024 + b] = logp;
    }
}

extern "C" void kernel_launch(void* const* d_in, const int* in_sizes, int n_in,
                              void* d_out, int out_size, void* d_ws, size_t ws_size,
                              hipStream_t stream) {
    const float* obs  = (const float*)d_in[0];
    const float* obst = (const float*)d_in[1];
    const float* eps  = (const float*)d_in[2];
    const float* W1   = (const float*)d_in[3];
    const float* b1   = (const float*)d_in[4];
    const float* W2   = (const float*)d_in[5];
    const float* b2   = (const float*)d_in[6];
    const float* muW  = (const float*)d_in[7];
    const float* mub  = (const float*)d_in[8];
    const float* lsW  = (const float*)d_in[9];
    const float* lsb  = (const float*)d_in[10];
    float* out = (float*)d_out;

    actor_kernel<<<512, 512, 0, stream>>>(obs, obst, eps, W1, b1, W2, b2,
                                          muW, mub, lsW, lsb, out);
}